// Round 3
// 208.391 us; speedup vs baseline: 1.0095x; 1.0095x over previous
//
#include <hip/hip_runtime.h>

// SmoothTopKGate: per row of 8 floats, solve sum_i sigmoid((s_i - theta)/tau) = k
// (k=2, tau=0.01) by safeguarded Newton, then emit the sigmoids.
//
// R4: two lanes per row; lane pairs cooperate via __shfl_xor(.,1) (DPP, no LDS).
// R5: kernel is latency-slack-bound, not throughput-bound (roofline 41us vs
// ~55us observed; harness fills dominate the bench total).
//   (a) ITEMS=2: each thread solves TWO independent rows (second float4 at
//       gid + n, still coalesced; n is even so lane-pair alignment holds and
//       pairs never straddle the bounds check) -> 2x ILP on the TRANS chain,
//       2x memory in flight, half the waves.
//   (b) Linearized final emit: o_i = m_i - d*ln2*m_i*(1-m_i) with
//       d = phi_new - phi_old (first-order Taylor, dm/dphi = -ln2*m(1-m)).
//       Replaces the final 4 exp2 + 4 rcp with 4 fma. After 2 full Newton
//       iterations the final step is <= ~0.004 phi-units even for an 8-way
//       tie, so the Taylor error is < 1e-5.
//   (c) Nontemporal load/store: every byte touched exactly once.
// R7: fix compile error — __builtin_nontemporal_load/store need a native
//     clang vector (ext_vector_type), not HIP's float4 class. Same codegen
//     (dwordx4 with nt bit), same logic.
//
// NOTE (correctness trap, do not "optimize"): g must be accumulated from the
// individual products m*(1-m) (or an fmaf chain thereof), NOT as
// f+2-sum(m^2) — catastrophic cancellation for ~40*tau gaps slams theta to
// the clamp bound (absmax ~0.95).

typedef float f32x4 __attribute__((ext_vector_type(4)));

__global__ __launch_bounds__(256) void smooth_topk_kernel(
    const float* __restrict__ s, float* __restrict__ out, int n) {
  constexpr int ITEMS = 2;
  int gid = blockIdx.x * blockDim.x + threadIdx.x;  // one float4 (half-row) per item
  if (gid >= n) return;

  const float C = 144.26950408889634f;      // 1/(tau*ln2), tau = 0.01
  const float LOG2E = 1.4426950408889634f;
  const float LN2 = 0.6931471805599453f;

  float v0[ITEMS], v1[ITEMS], v2[ITEMS], v3[ITEMS];
  float phi[ITEMS], lo[ITEMS], hi[ITEMS];

#pragma unroll
  for (int u = 0; u < ITEMS; ++u) {
    f32x4 v4 = __builtin_nontemporal_load(
        reinterpret_cast<const f32x4*>(s) + (gid + u * n));
    v0[u] = v4.x * C;
    v1[u] = v4.y * C;
    v2[u] = v4.z * C;
    v3[u] = v4.w * C;

    // ---- top-3 of my quad (p1 >= p2 >= p3), scaled domain ----
    float a = fmaxf(v0[u], v1[u]), b = fminf(v0[u], v1[u]);
    float c = fmaxf(v2[u], v3[u]), d = fminf(v2[u], v3[u]);
    float mn = fminf(a, c);
    float p1 = fmaxf(a, c);
    float p2 = fmaxf(mn, fmaxf(b, d));
    float p3 = __builtin_amdgcn_fmed3f(b, d, mn);

    // ---- partner quad's top-3 via xor-1 shuffle (DPP quad_perm) ----
    float q1 = __shfl_xor(p1, 1, 64);
    float q2 = __shfl_xor(p2, 1, 64);
    float q3 = __shfl_xor(p3, 1, 64);

    // 2nd and 3rd largest of the union (symmetric in p<->q: both lanes agree)
    float t2 = fmaxf(fminf(p1, q1), fmaxf(p2, q2));
    float t3 = fmaxf(fmaxf(fminf(p2, q1), fminf(p1, q2)), fmaxf(p3, q3));

    phi[u] = 0.5f * (t2 + t3);  // scaled theta; exact for 2-active case
    lo[u] = t3 - 4.33f;         // root provably within ~0.025/tau scaled
    hi[u] = t2 + 4.33f;
  }

  // ---- 2 full Newton iterations (independent across items -> ILP) ----
#pragma unroll
  for (int it = 0; it < 2; ++it) {
#pragma unroll
    for (int u = 0; u < ITEMS; ++u) {
      float e0 = __builtin_amdgcn_exp2f(phi[u] - v0[u]);
      float e1 = __builtin_amdgcn_exp2f(phi[u] - v1[u]);
      float e2 = __builtin_amdgcn_exp2f(phi[u] - v2[u]);
      float e3 = __builtin_amdgcn_exp2f(phi[u] - v3[u]);
      float m0 = __builtin_amdgcn_rcpf(1.0f + e0);  // rcp(inf)=0: no NaN
      float m1 = __builtin_amdgcn_rcpf(1.0f + e1);
      float m2 = __builtin_amdgcn_rcpf(1.0f + e2);
      float m3 = __builtin_amdgcn_rcpf(1.0f + e3);
      float fh = (m0 + m1) + (m2 + m3);
      float gh = fmaf(m0, 1.0f - m0, fmaf(m1, 1.0f - m1,
                 fmaf(m2, 1.0f - m2, m3 * (1.0f - m3))));
      float f = (fh + __shfl_xor(fh, 1, 64)) - 2.0f;  // commutative: lanes agree
      float g = gh + __shfl_xor(gh, 1, 64);
      float step = f * LOG2E * __builtin_amdgcn_rcpf(fmaxf(g, 1e-12f));
      phi[u] = fminf(fmaxf(phi[u] + step, lo[u]), hi[u]);
    }
  }

  // ---- final iteration: compute m, take step, emit linearized sigmoids ----
#pragma unroll
  for (int u = 0; u < ITEMS; ++u) {
    float e0 = __builtin_amdgcn_exp2f(phi[u] - v0[u]);
    float e1 = __builtin_amdgcn_exp2f(phi[u] - v1[u]);
    float e2 = __builtin_amdgcn_exp2f(phi[u] - v2[u]);
    float e3 = __builtin_amdgcn_exp2f(phi[u] - v3[u]);
    float m0 = __builtin_amdgcn_rcpf(1.0f + e0);
    float m1 = __builtin_amdgcn_rcpf(1.0f + e1);
    float m2 = __builtin_amdgcn_rcpf(1.0f + e2);
    float m3 = __builtin_amdgcn_rcpf(1.0f + e3);
    float c0 = m0 * (1.0f - m0);
    float c1 = m1 * (1.0f - m1);
    float c2 = m2 * (1.0f - m2);
    float c3 = m3 * (1.0f - m3);
    float fh = (m0 + m1) + (m2 + m3);
    float gh = (c0 + c1) + (c2 + c3);
    float f = (fh + __shfl_xor(fh, 1, 64)) - 2.0f;
    float g = gh + __shfl_xor(gh, 1, 64);
    float step = f * LOG2E * __builtin_amdgcn_rcpf(fmaxf(g, 1e-12f));
    float phin = fminf(fmaxf(phi[u] + step, lo[u]), hi[u]);
    float w = (phin - phi[u]) * LN2;  // actual (clamped) delta, in ln-units

    f32x4 o;
    o.x = fmaf(-w, c0, m0);
    o.y = fmaf(-w, c1, m1);
    o.z = fmaf(-w, c2, m2);
    o.w = fmaf(-w, c3, m3);
    __builtin_nontemporal_store(o, reinterpret_cast<f32x4*>(out) + (gid + u * n));
  }
}

extern "C" void kernel_launch(void* const* d_in, const int* in_sizes, int n_in,
                              void* d_out, int out_size, void* d_ws, size_t ws_size,
                              hipStream_t stream) {
  const float* s = (const float*)d_in[0];
  float* out = (float*)d_out;
  int nhalf = in_sizes[0] / 4;  // number of float4 half-rows (2 per row)
  int n = nhalf >> 1;           // items per template slot (ITEMS=2)
  int block = 256;
  int grid = (n + block - 1) / block;
  smooth_topk_kernel<<<grid, block, 0, stream>>>(s, out, n);
}